// Round 7
// baseline (27.244 us; speedup 1.0000x reference)
//
#include <hip/hip_runtime.h>

// OversizeConv2d via MFMA: Z = A_h * X * A_w^T + hb*s_w[ow] + wb per (b,c) image.
// v7: Toeplitz factors stored as compressed 16-row BAND matrices M[r][t]=tap[t-r+63]
// (row 16nt+r of the full matrix = band row r at column offset -16nt), bf16 taps.
// LDS ~26.9 KB -> 6 blocks/CU (24 waves/CU) vs 4 before; no register hoisting.
// Block = one channel, 2 images; grid 2048.

#define STRB 72    // Xs/PT row stride (elems): 144 B, 16B-aligned rows, 2-way banks
#define MSTR 120   // band row stride (elems): 240 B, 16B-aligned, benign banks

typedef short  bfrag  __attribute__((ext_vector_type(8)));   // 8 bf16 = 4 VGPR
typedef float  f32x4  __attribute__((ext_vector_type(4)));
typedef unsigned short us4 __attribute__((ext_vector_type(4)));

__device__ __forceinline__ unsigned short f2bf(float f) {
    unsigned u = __builtin_bit_cast(unsigned, f);
    u += 0x7fffu + ((u >> 16) & 1u);          // round-to-nearest-even
    return (unsigned short)(u >> 16);
}
__device__ __forceinline__ float bf2f(unsigned short h) {
    unsigned u = ((unsigned)h) << 16;
    return __builtin_bit_cast(float, u);
}

// LDS-visibility barrier WITHOUT vmcnt drain (keeps global loads/stores in flight)
__device__ __forceinline__ void lds_barrier() {
    asm volatile("s_waitcnt lgkmcnt(0)" ::: "memory");
    __builtin_amdgcn_s_barrier();
}

__global__ __launch_bounds__(256, 6)
void oversize_conv_v7(const float* __restrict__ x,
                      const float* __restrict__ hwt,   // (128,1,13,1)
                      const float* __restrict__ wwt,   // (128,1,1,13)
                      const float* __restrict__ hb,
                      const float* __restrict__ wb,
                      float* __restrict__ out)
{
    __shared__ __align__(16) unsigned short Xs[64 * STRB];   // X bf16 [h][w]
    __shared__ __align__(16) unsigned short PT[64 * STRB];   // P^T [ow][h]
    __shared__ __align__(16) unsigned short Mw[16 * MSTR];   // band: Mw[r][t]=wk[t-r+15]
    __shared__ __align__(16) unsigned short Mh[16 * MSTR];   // band: Mh[r][t]=hk[t-r+15]
    __shared__ unsigned short hkb[128], wkb[128];            // bf16 taps
    __shared__ __align__(16) float sw[64];

    const int tid = threadIdx.x;
    const int c    = blockIdx.x & 127;         // channel
    const int pair = blockIdx.x >> 7;          // batches 2*pair, 2*pair+1
    const size_t imgStride = (size_t)128 * 4096;
    const size_t img0 = ((size_t)(2 * pair) * 128 + c) * 4096;

    const int wv = tid >> 6, lane = tid & 63;
    const int r = lane & 15, gq = lane >> 4;

    // ---- image 0 -> regs, fully coalesced (issue before setup math)
    float4 xv[4];
    {
        const float4* xg = (const float4*)(x + img0);
        #pragma unroll
        for (int q = 0; q < 4; ++q) xv[q] = xg[tid + q * 256];
    }

    // ---- interpolate 13 -> 127 taps (align_corners linear), store bf16
    if (tid < 127) {
        const float scale = 12.0f / 126.0f;
        float pos = (float)tid * scale;
        int   lo  = (int)pos;
        float fr  = pos - (float)lo;
        int   hi  = (lo + 1 < 12) ? lo + 1 : 12;
        hkb[tid] = f2bf(hwt[c * 13 + lo] * (1.0f - fr) + hwt[c * 13 + hi] * fr);
        wkb[tid] = f2bf(wwt[c * 13 + lo] * (1.0f - fr) + wwt[c * 13 + hi] * fr);
    }
    lds_barrier();

    // ---- build band matrices: M[r][t] = tap[t - r + 15], t in [0,112)
    //      (full Toeplitz row 16nt+r, col range [0,64): tap[col-(16nt+r)+63]
    //       = M[r][col - 16nt + 48])
    for (int k = tid; k < 16 * 112; k += 256) {
        int rr  = k / 112;
        int col = k - rr * 112;
        int t   = col + 15 - rr;               // in [0,126]
        Mw[rr * MSTR + col] = wkb[t];
        Mh[rr * MSTR + col] = hkb[t];
    }
    // ---- s_w[ow] = sum_iw wk[iw-ow+63]  (bf16 taps, f32 accumulate)
    if (tid < 64) {
        float s = 0.f;
        #pragma unroll 8
        for (int iw = 0; iw < 64; ++iw) s += bf2f(wkb[iw - tid + 63]);
        sw[tid] = s;
    }
    // ---- stage image 0 into Xs
    #pragma unroll
    for (int q = 0; q < 4; ++q) {
        int idx = tid + q * 256;
        int row = idx >> 4;
        int col = (idx & 15) * 4;
        us4 v;
        v[0] = f2bf(xv[q].x); v[1] = f2bf(xv[q].y);
        v[2] = f2bf(xv[q].z); v[3] = f2bf(xv[q].w);
        *(us4*)&Xs[row * STRB + col] = v;
    }
    // ---- prefetch image 1 (consumed at the tail of iter 0)
    float4 xn[4];
    {
        const float4* xg = (const float4*)(x + img0 + imgStride);
        #pragma unroll
        for (int q = 0; q < 4; ++q) xn[q] = xg[tid + q * 256];
    }
    lds_barrier();   // taps/bands/sw/Xs visible

    const float hbc = hb[c], wbc = wb[c];
    f32x4 sw4 = *(const f32x4*)&sw[16 * wv + 4 * gq];
    f32x4 bias;
    bias[0] = hbc * sw4[0] + wbc; bias[1] = hbc * sw4[1] + wbc;
    bias[2] = hbc * sw4[2] + wbc; bias[3] = hbc * sw4[3] + wbc;

    #pragma unroll
    for (int i = 0; i < 2; ++i) {
        // ---- pass A: P = X * Aw^T (wave wv owns P rows 16wv..16wv+15)
        bfrag a0 = *(const bfrag*)&Xs[(16 * wv + r) * STRB + 8 * gq];
        bfrag a1 = *(const bfrag*)&Xs[(16 * wv + r) * STRB + 32 + 8 * gq];
        f32x4 acc[4] = {};
        #pragma unroll
        for (int nt = 0; nt < 4; ++nt) {
            const int mb = r * MSTR + 8 * gq - 16 * nt + 48;
            bfrag b0 = *(const bfrag*)&Mw[mb];
            bfrag b1 = *(const bfrag*)&Mw[mb + 32];
            acc[nt] = __builtin_amdgcn_mfma_f32_16x16x32_bf16(a0, b0, acc[nt], 0, 0, 0);
            acc[nt] = __builtin_amdgcn_mfma_f32_16x16x32_bf16(a1, b1, acc[nt], 0, 0, 0);
        }
        // ---- write P transposed: PT[ow=16nt+r][h=16wv+4gq+j]
        #pragma unroll
        for (int nt = 0; nt < 4; ++nt) {
            us4 p;
            p[0] = f2bf(acc[nt][0]); p[1] = f2bf(acc[nt][1]);
            p[2] = f2bf(acc[nt][2]); p[3] = f2bf(acc[nt][3]);
            *(us4*)&PT[(16 * nt + r) * STRB + 16 * wv + 4 * gq] = p;
        }
        lds_barrier();   // PT visible; all Xs reads done

        // ---- pass B (swapped): Z^T = PT * Ah^T
        bfrag pa0 = *(const bfrag*)&PT[(16 * wv + r) * STRB + 8 * gq];
        bfrag pa1 = *(const bfrag*)&PT[(16 * wv + r) * STRB + 32 + 8 * gq];
        f32x4 acc2[4] = {bias, bias, bias, bias};
        #pragma unroll
        for (int nt = 0; nt < 4; ++nt) {
            const int mb = r * MSTR + 8 * gq - 16 * nt + 48;
            bfrag bh0 = *(const bfrag*)&Mh[mb];
            bfrag bh1 = *(const bfrag*)&Mh[mb + 32];
            acc2[nt] = __builtin_amdgcn_mfma_f32_16x16x32_bf16(pa0, bh0, acc2[nt], 0, 0, 0);
            acc2[nt] = __builtin_amdgcn_mfma_f32_16x16x32_bf16(pa1, bh1, acc2[nt], 0, 0, 0);
        }

        // ---- stage image 1 into Xs (pass-A Xs reads completed before mid barrier)
        if (i == 0) {
            #pragma unroll
            for (int q = 0; q < 4; ++q) {
                int idx = tid + q * 256;
                int row = idx >> 4;
                int col = (idx & 15) * 4;
                us4 v;
                v[0] = f2bf(xn[q].x); v[1] = f2bf(xn[q].y);
                v[2] = f2bf(xn[q].z); v[3] = f2bf(xn[q].w);
                *(us4*)&Xs[row * STRB + col] = v;
            }
        }

        // ---- store Z[i]: lane holds Z[oh=16nt+r][ow=16wv+4gq+j], j-contiguous f32x4
        {
            float* og = out + img0 + (size_t)i * imgStride;
            #pragma unroll
            for (int nt = 0; nt < 4; ++nt) {
                f32x4 v = acc2[nt];
                *(f32x4*)&og[(size_t)(16 * nt + r) * 64 + 16 * wv + 4 * gq] = v;
            }
        }

        lds_barrier();   // Xs[1] visible; all PT reads done
    }
}

extern "C" void kernel_launch(void* const* d_in, const int* in_sizes, int n_in,
                              void* d_out, int out_size, void* d_ws, size_t ws_size,
                              hipStream_t stream)
{
    const float* x   = (const float*)d_in[0];
    const float* hwt = (const float*)d_in[1];
    const float* wwt = (const float*)d_in[2];
    const float* hb  = (const float*)d_in[3];
    const float* wb  = (const float*)d_in[4];
    oversize_conv_v7<<<2048, 256, 0, stream>>>(x, hwt, wwt, hb, wb, (float*)d_out);
}

// Round 8
// 25.454 us; speedup vs baseline: 1.0703x; 1.0703x over previous
//
#include <hip/hip_runtime.h>

// OversizeConv2d via MFMA: Z = A_h * X * A_w^T + hb*s_w[ow] + wb per (b,c) image.
// v8: wave-owned COLUMN tiles. Pass A: wave wv computes P[:, 16wv..16wv+15]
// (all 4 row-tiles m) -> writes PT rows 16wv..+15 = its OWN pass-B A-fragment rows.
// PT is wave-private => no barrier between pass A and pass B (intra-wave LDS
// ordering suffices). Xs double-buffered => ONE barrier per image total.
// Toeplitz factors as 16-row band matrices (v7). Block = 1 channel x 4 images.

#define STRB 72    // Xs/PT row stride (elems): 144 B
#define MSTR 120   // band row stride (elems): 240 B

typedef short  bfrag  __attribute__((ext_vector_type(8)));   // 8 bf16 = 4 VGPR
typedef float  f32x4  __attribute__((ext_vector_type(4)));
typedef unsigned short us4 __attribute__((ext_vector_type(4)));

__device__ __forceinline__ unsigned short f2bf(float f) {
    unsigned u = __builtin_bit_cast(unsigned, f);
    u += 0x7fffu + ((u >> 16) & 1u);          // round-to-nearest-even
    return (unsigned short)(u >> 16);
}
__device__ __forceinline__ float bf2f(unsigned short h) {
    unsigned u = ((unsigned)h) << 16;
    return __builtin_bit_cast(float, u);
}

// LDS-visibility barrier WITHOUT vmcnt drain (keeps global loads/stores in flight)
__device__ __forceinline__ void lds_barrier() {
    asm volatile("s_waitcnt lgkmcnt(0)" ::: "memory");
    __builtin_amdgcn_s_barrier();
}

__global__ __launch_bounds__(256, 4)
void oversize_conv_v8(const float* __restrict__ x,
                      const float* __restrict__ hwt,   // (128,1,13,1)
                      const float* __restrict__ wwt,   // (128,1,1,13)
                      const float* __restrict__ hb,
                      const float* __restrict__ wb,
                      float* __restrict__ out)
{
    __shared__ __align__(16) unsigned short Xs[2][64 * STRB]; // X bf16, double-buffered
    __shared__ __align__(16) unsigned short PT[64 * STRB];    // P^T [ow][h], wave-private rows
    __shared__ __align__(16) unsigned short Mw[16 * MSTR];    // band: Mw[r][t]=wk[t-r+15]
    __shared__ __align__(16) unsigned short Mh[16 * MSTR];    // band: Mh[r][t]=hk[t-r+15]
    __shared__ unsigned short hkb[128], wkb[128];             // bf16 taps
    __shared__ __align__(16) float sw[64];

    const int tid = threadIdx.x;
    const int c   = blockIdx.x & 127;          // channel
    const int g4  = blockIdx.x >> 7;           // batches 4*g4 .. 4*g4+3
    const size_t imgStride = (size_t)128 * 4096;
    const size_t img0 = ((size_t)(4 * g4) * 128 + c) * 4096;

    const int wv = tid >> 6, lane = tid & 63;
    const int r = lane & 15, gq = lane >> 4;

    // ---- image 0 -> regs, fully coalesced (issue before setup math)
    float4 xv[4];
    {
        const float4* xg = (const float4*)(x + img0);
        #pragma unroll
        for (int q = 0; q < 4; ++q) xv[q] = xg[tid + q * 256];
    }

    // ---- interpolate 13 -> 127 taps (align_corners linear), bf16
    if (tid < 127) {
        const float scale = 12.0f / 126.0f;
        float pos = (float)tid * scale;
        int   lo  = (int)pos;
        float fr  = pos - (float)lo;
        int   hi  = (lo + 1 < 12) ? lo + 1 : 12;
        hkb[tid] = f2bf(hwt[c * 13 + lo] * (1.0f - fr) + hwt[c * 13 + hi] * fr);
        wkb[tid] = f2bf(wwt[c * 13 + lo] * (1.0f - fr) + wwt[c * 13 + hi] * fr);
    }
    lds_barrier();

    // ---- band matrices: M[r][t] = tap[t - r + 15], t in [0,112)
    //      full-Toeplitz row 16n+r, col k  ->  M[r][k - 16n + 48]
    for (int k = tid; k < 16 * 112; k += 256) {
        int rr  = k / 112;
        int col = k - rr * 112;
        int t   = col + 15 - rr;               // in [0,126]
        Mw[rr * MSTR + col] = wkb[t];
        Mh[rr * MSTR + col] = hkb[t];
    }
    // ---- s_w[ow] = sum_iw wk[iw-ow+63]
    if (tid < 64) {
        float s = 0.f;
        #pragma unroll 8
        for (int iw = 0; iw < 64; ++iw) s += bf2f(wkb[iw - tid + 63]);
        sw[tid] = s;
    }
    // ---- stage image 0 into Xs[0]
    #pragma unroll
    for (int q = 0; q < 4; ++q) {
        int idx = tid + q * 256;
        int row = idx >> 4;
        int col = (idx & 15) * 4;
        us4 v;
        v[0] = f2bf(xv[q].x); v[1] = f2bf(xv[q].y);
        v[2] = f2bf(xv[q].z); v[3] = f2bf(xv[q].w);
        *(us4*)&Xs[0][row * STRB + col] = v;
    }
    // ---- prefetch image 1
    float4 xn[4];
    {
        const float4* xg = (const float4*)(x + img0 + imgStride);
        #pragma unroll
        for (int q = 0; q < 4; ++q) xn[q] = xg[tid + q * 256];
    }
    lds_barrier();   // taps/bands/sw/Xs[0] visible

    // ---- hoist pass-A B-fragments (nt = wv fixed): 8 VGPR
    const int mbase = r * MSTR + 8 * gq + 48;
    bfrag bW0 = *(const bfrag*)&Mw[mbase - 16 * wv];
    bfrag bW1 = *(const bfrag*)&Mw[mbase - 16 * wv + 32];

    const float hbc = hb[c], wbc = wb[c];
    f32x4 sw4 = *(const f32x4*)&sw[16 * wv + 4 * gq];
    f32x4 bias;
    bias[0] = hbc * sw4[0] + wbc; bias[1] = hbc * sw4[1] + wbc;
    bias[2] = hbc * sw4[2] + wbc; bias[3] = hbc * sw4[3] + wbc;

    #pragma unroll
    for (int i = 0; i < 4; ++i) {
        const unsigned short* xb = Xs[i & 1];

        // ---- pass A: P[:, 16wv..+15] = X * Aw^T col-tile; iterate row-tiles m
        f32x4 accA[4] = {};
        #pragma unroll
        for (int m = 0; m < 4; ++m) {
            bfrag a0 = *(const bfrag*)&xb[(16 * m + r) * STRB + 8 * gq];
            bfrag a1 = *(const bfrag*)&xb[(16 * m + r) * STRB + 32 + 8 * gq];
            accA[m] = __builtin_amdgcn_mfma_f32_16x16x32_bf16(a0, bW0, accA[m], 0, 0, 0);
            accA[m] = __builtin_amdgcn_mfma_f32_16x16x32_bf16(a1, bW1, accA[m], 0, 0, 0);
        }
        // ---- write PT rows 16wv..+15 (own slice): PT[ow=16wv+r][h=16m+4gq+j]
        #pragma unroll
        for (int m = 0; m < 4; ++m) {
            us4 p;
            p[0] = f2bf(accA[m][0]); p[1] = f2bf(accA[m][1]);
            p[2] = f2bf(accA[m][2]); p[3] = f2bf(accA[m][3]);
            *(us4*)&PT[(16 * wv + r) * STRB + 16 * m + 4 * gq] = p;
        }
        // NO barrier: pass B reads only this wave's PT rows (intra-wave LDS order)

        // ---- pass B (swapped): Z^T = PT * Ah^T; A-frag = own PT rows
        bfrag pa0 = *(const bfrag*)&PT[(16 * wv + r) * STRB + 8 * gq];
        bfrag pa1 = *(const bfrag*)&PT[(16 * wv + r) * STRB + 32 + 8 * gq];
        f32x4 acc2[4] = {bias, bias, bias, bias};
        #pragma unroll
        for (int nt = 0; nt < 4; ++nt) {
            bfrag bh0 = *(const bfrag*)&Mh[mbase - 16 * nt];
            bfrag bh1 = *(const bfrag*)&Mh[mbase - 16 * nt + 32];
            acc2[nt] = __builtin_amdgcn_mfma_f32_16x16x32_bf16(pa0, bh0, acc2[nt], 0, 0, 0);
            acc2[nt] = __builtin_amdgcn_mfma_f32_16x16x32_bf16(pa1, bh1, acc2[nt], 0, 0, 0);
        }

        // ---- stage image i+1 into the ALT buffer (no wait on other waves)
        if (i < 3) {
            unsigned short* xalt = (unsigned short*)Xs[(i + 1) & 1];
            #pragma unroll
            for (int q = 0; q < 4; ++q) {
                int idx = tid + q * 256;
                int row = idx >> 4;
                int col = (idx & 15) * 4;
                us4 v;
                v[0] = f2bf(xn[q].x); v[1] = f2bf(xn[q].y);
                v[2] = f2bf(xn[q].z); v[3] = f2bf(xn[q].w);
                *(us4*)&xalt[row * STRB + col] = v;
            }
        }
        // ---- refill prefetch with image i+2
        if (i < 2) {
            const float4* xg = (const float4*)(x + img0 + (size_t)(i + 2) * imgStride);
            #pragma unroll
            for (int q = 0; q < 4; ++q) xn[q] = xg[tid + q * 256];
        }

        // ---- store Z[i]: lane holds Z[oh=16nt+r][ow=16wv+4gq+j], j-contiguous
        {
            float* og = out + img0 + (size_t)i * imgStride;
            #pragma unroll
            for (int nt = 0; nt < 4; ++nt) {
                f32x4 v = acc2[nt];
                *(f32x4*)&og[(size_t)(16 * nt + r) * 64 + 16 * wv + 4 * gq] = v;
            }
        }

        lds_barrier();   // single rendezvous: Xs[(i+1)&1] visible for next pass A
    }
}

extern "C" void kernel_launch(void* const* d_in, const int* in_sizes, int n_in,
                              void* d_out, int out_size, void* d_ws, size_t ws_size,
                              hipStream_t stream)
{
    const float* x   = (const float*)d_in[0];
    const float* hwt = (const float*)d_in[1];
    const float* wwt = (const float*)d_in[2];
    const float* hb  = (const float*)d_in[3];
    const float* wb  = (const float*)d_in[4];
    oversize_conv_v8<<<1024, 256, 0, stream>>>(x, hwt, wwt, hb, wb, (float*)d_out);
}

// Round 9
// 25.425 us; speedup vs baseline: 1.0715x; 1.0012x over previous
//
#include <hip/hip_runtime.h>

// OversizeConv2d via MFMA: Z = A_h * X * A_w^T + hb*s_w[ow] + wb per (b,c) image.
// v9 = v8 (wave-owned column tiles, wave-private PT, 1 barrier/image) +
//  k-split pass B: pass-B k-half0 (P rows 0..31) starts right after pass-A m0,m1
//  PT writes, overlapping pass-A m2,m3 -> shorter per-image dependency chain.
//  Double prefetch buffers: image i+2 loads issue at the TOP of iteration i.

#define STRB 72    // Xs/PT row stride (elems): 144 B
#define MSTR 120   // band row stride (elems): 240 B

typedef short  bfrag  __attribute__((ext_vector_type(8)));   // 8 bf16 = 4 VGPR
typedef float  f32x4  __attribute__((ext_vector_type(4)));
typedef unsigned short us4 __attribute__((ext_vector_type(4)));

__device__ __forceinline__ unsigned short f2bf(float f) {
    unsigned u = __builtin_bit_cast(unsigned, f);
    u += 0x7fffu + ((u >> 16) & 1u);          // round-to-nearest-even
    return (unsigned short)(u >> 16);
}
__device__ __forceinline__ float bf2f(unsigned short h) {
    unsigned u = ((unsigned)h) << 16;
    return __builtin_bit_cast(float, u);
}

// LDS-visibility barrier WITHOUT vmcnt drain (keeps global loads/stores in flight)
__device__ __forceinline__ void lds_barrier() {
    asm volatile("s_waitcnt lgkmcnt(0)" ::: "memory");
    __builtin_amdgcn_s_barrier();
}

__global__ __launch_bounds__(256, 4)
void oversize_conv_v9(const float* __restrict__ x,
                      const float* __restrict__ hwt,   // (128,1,13,1)
                      const float* __restrict__ wwt,   // (128,1,1,13)
                      const float* __restrict__ hb,
                      const float* __restrict__ wb,
                      float* __restrict__ out)
{
    __shared__ __align__(16) unsigned short Xs[2][64 * STRB]; // X bf16, double-buffered
    __shared__ __align__(16) unsigned short PT[64 * STRB];    // P^T [ow][h], wave-private rows
    __shared__ __align__(16) unsigned short Mw[16 * MSTR];    // band: Mw[r][t]=wk[t-r+15]
    __shared__ __align__(16) unsigned short Mh[16 * MSTR];    // band: Mh[r][t]=hk[t-r+15]
    __shared__ unsigned short hkb[128], wkb[128];             // bf16 taps
    __shared__ __align__(16) float sw[64];

    const int tid = threadIdx.x;
    const int c   = blockIdx.x & 127;          // channel
    const int g4  = blockIdx.x >> 7;           // batches 4*g4 .. 4*g4+3
    const size_t imgStride = (size_t)128 * 4096;
    const size_t img0 = ((size_t)(4 * g4) * 128 + c) * 4096;

    const int wv = tid >> 6, lane = tid & 63;
    const int r = lane & 15, gq = lane >> 4;

    // ---- image 0 -> regs, fully coalesced (issue before setup math)
    float4 xv[4];
    {
        const float4* xg = (const float4*)(x + img0);
        #pragma unroll
        for (int q = 0; q < 4; ++q) xv[q] = xg[tid + q * 256];
    }

    // ---- interpolate 13 -> 127 taps (align_corners linear), bf16
    if (tid < 127) {
        const float scale = 12.0f / 126.0f;
        float pos = (float)tid * scale;
        int   lo  = (int)pos;
        float fr  = pos - (float)lo;
        int   hi  = (lo + 1 < 12) ? lo + 1 : 12;
        hkb[tid] = f2bf(hwt[c * 13 + lo] * (1.0f - fr) + hwt[c * 13 + hi] * fr);
        wkb[tid] = f2bf(wwt[c * 13 + lo] * (1.0f - fr) + wwt[c * 13 + hi] * fr);
    }
    lds_barrier();

    // ---- band matrices: M[r][t] = tap[t - r + 15], t in [0,112)
    //      full-Toeplitz row 16n+r, col k  ->  M[r][k - 16n + 48]
    for (int k = tid; k < 16 * 112; k += 256) {
        int rr  = k / 112;
        int col = k - rr * 112;
        int t   = col + 15 - rr;               // in [0,126]
        Mw[rr * MSTR + col] = wkb[t];
        Mh[rr * MSTR + col] = hkb[t];
    }
    // ---- s_w[ow] = sum_iw wk[iw-ow+63]
    if (tid < 64) {
        float s = 0.f;
        #pragma unroll 8
        for (int iw = 0; iw < 64; ++iw) s += bf2f(wkb[iw - tid + 63]);
        sw[tid] = s;
    }
    // ---- stage image 0 into Xs[0]
    #pragma unroll
    for (int q = 0; q < 4; ++q) {
        int idx = tid + q * 256;
        int row = idx >> 4;
        int col = (idx & 15) * 4;
        us4 v;
        v[0] = f2bf(xv[q].x); v[1] = f2bf(xv[q].y);
        v[2] = f2bf(xv[q].z); v[3] = f2bf(xv[q].w);
        *(us4*)&Xs[0][row * STRB + col] = v;
    }
    // ---- prefetch image 1 into ping buffer
    float4 xn[2][4];
    {
        const float4* xg = (const float4*)(x + img0 + imgStride);
        #pragma unroll
        for (int q = 0; q < 4; ++q) xn[0][q] = xg[tid + q * 256];
    }
    lds_barrier();   // taps/bands/sw/Xs[0] visible

    // ---- hoist pass-A B-fragments (nt = wv fixed): 8 VGPR
    const int mbase = r * MSTR + 8 * gq + 48;
    bfrag bW0 = *(const bfrag*)&Mw[mbase - 16 * wv];
    bfrag bW1 = *(const bfrag*)&Mw[mbase - 16 * wv + 32];

    const float hbc = hb[c], wbc = wb[c];
    f32x4 sw4 = *(const f32x4*)&sw[16 * wv + 4 * gq];
    f32x4 bias;
    bias[0] = hbc * sw4[0] + wbc; bias[1] = hbc * sw4[1] + wbc;
    bias[2] = hbc * sw4[2] + wbc; bias[3] = hbc * sw4[3] + wbc;

    const int ptrow = (16 * wv + r) * STRB;    // own PT row base

    #pragma unroll
    for (int i = 0; i < 4; ++i) {
        const unsigned short* xb = Xs[i & 1];

        // ---- issue global prefetch for image i+2 EARLY (deepest cover)
        if (i < 2) {
            const float4* xg = (const float4*)(x + img0 + (size_t)(i + 2) * imgStride);
            #pragma unroll
            for (int q = 0; q < 4; ++q) xn[(i + 1) & 1][q] = xg[tid + q * 256];
        }

        // ---- pass A, m = 0,1 (k-half 0 of pass B)
        f32x4 accA0 = {}, accA1 = {};
        {
            bfrag a00 = *(const bfrag*)&xb[(r) * STRB + 8 * gq];
            bfrag a01 = *(const bfrag*)&xb[(r) * STRB + 32 + 8 * gq];
            bfrag a10 = *(const bfrag*)&xb[(16 + r) * STRB + 8 * gq];
            bfrag a11 = *(const bfrag*)&xb[(16 + r) * STRB + 32 + 8 * gq];
            accA0 = __builtin_amdgcn_mfma_f32_16x16x32_bf16(a00, bW0, accA0, 0, 0, 0);
            accA0 = __builtin_amdgcn_mfma_f32_16x16x32_bf16(a01, bW1, accA0, 0, 0, 0);
            accA1 = __builtin_amdgcn_mfma_f32_16x16x32_bf16(a10, bW0, accA1, 0, 0, 0);
            accA1 = __builtin_amdgcn_mfma_f32_16x16x32_bf16(a11, bW1, accA1, 0, 0, 0);
        }
        // PT own-row cols 0..31 (m=0 -> cols 0..15, m=1 -> 16..31)
        {
            us4 p0, p1;
            p0[0] = f2bf(accA0[0]); p0[1] = f2bf(accA0[1]);
            p0[2] = f2bf(accA0[2]); p0[3] = f2bf(accA0[3]);
            p1[0] = f2bf(accA1[0]); p1[1] = f2bf(accA1[1]);
            p1[2] = f2bf(accA1[2]); p1[3] = f2bf(accA1[3]);
            *(us4*)&PT[ptrow + 4 * gq]      = p0;
            *(us4*)&PT[ptrow + 16 + 4 * gq] = p1;
        }

        // ---- pass B k-half 0: overlaps pass-A m2,m3 below
        f32x4 acc2[4] = {bias, bias, bias, bias};
        {
            bfrag pa0 = *(const bfrag*)&PT[ptrow + 8 * gq];
            #pragma unroll
            for (int nt = 0; nt < 4; ++nt) {
                bfrag bh0 = *(const bfrag*)&Mh[mbase - 16 * nt];
                acc2[nt] = __builtin_amdgcn_mfma_f32_16x16x32_bf16(pa0, bh0, acc2[nt], 0, 0, 0);
            }
        }

        // ---- pass A, m = 2,3 (k-half 1 of pass B)
        f32x4 accA2 = {}, accA3 = {};
        {
            bfrag a20 = *(const bfrag*)&xb[(32 + r) * STRB + 8 * gq];
            bfrag a21 = *(const bfrag*)&xb[(32 + r) * STRB + 32 + 8 * gq];
            bfrag a30 = *(const bfrag*)&xb[(48 + r) * STRB + 8 * gq];
            bfrag a31 = *(const bfrag*)&xb[(48 + r) * STRB + 32 + 8 * gq];
            accA2 = __builtin_amdgcn_mfma_f32_16x16x32_bf16(a20, bW0, accA2, 0, 0, 0);
            accA2 = __builtin_amdgcn_mfma_f32_16x16x32_bf16(a21, bW1, accA2, 0, 0, 0);
            accA3 = __builtin_amdgcn_mfma_f32_16x16x32_bf16(a30, bW0, accA3, 0, 0, 0);
            accA3 = __builtin_amdgcn_mfma_f32_16x16x32_bf16(a31, bW1, accA3, 0, 0, 0);
        }
        {
            us4 p2, p3;
            p2[0] = f2bf(accA2[0]); p2[1] = f2bf(accA2[1]);
            p2[2] = f2bf(accA2[2]); p2[3] = f2bf(accA2[3]);
            p3[0] = f2bf(accA3[0]); p3[1] = f2bf(accA3[1]);
            p3[2] = f2bf(accA3[2]); p3[3] = f2bf(accA3[3]);
            *(us4*)&PT[ptrow + 32 + 4 * gq] = p2;
            *(us4*)&PT[ptrow + 48 + 4 * gq] = p3;
        }

        // ---- pass B k-half 1
        {
            bfrag pa1 = *(const bfrag*)&PT[ptrow + 32 + 8 * gq];
            #pragma unroll
            for (int nt = 0; nt < 4; ++nt) {
                bfrag bh1 = *(const bfrag*)&Mh[mbase - 16 * nt + 32];
                acc2[nt] = __builtin_amdgcn_mfma_f32_16x16x32_bf16(pa1, bh1, acc2[nt], 0, 0, 0);
            }
        }

        // ---- stage image i+1 into ALT buffer (after all pa reads; disjoint from PT)
        if (i < 3) {
            unsigned short* xalt = (unsigned short*)Xs[(i + 1) & 1];
            #pragma unroll
            for (int q = 0; q < 4; ++q) {
                int idx = tid + q * 256;
                int row = idx >> 4;
                int col = (idx & 15) * 4;
                us4 v;
                v[0] = f2bf(xn[i & 1][q].x); v[1] = f2bf(xn[i & 1][q].y);
                v[2] = f2bf(xn[i & 1][q].z); v[3] = f2bf(xn[i & 1][q].w);
                *(us4*)&xalt[row * STRB + col] = v;
            }
        }

        // ---- store Z[i]: lane holds Z[oh=16nt+r][ow=16wv+4gq+j], j-contiguous
        {
            float* og = out + img0 + (size_t)i * imgStride;
            #pragma unroll
            for (int nt = 0; nt < 4; ++nt) {
                f32x4 v = acc2[nt];
                *(f32x4*)&og[(size_t)(16 * nt + r) * 64 + 16 * wv + 4 * gq] = v;
            }
        }

        lds_barrier();   // single rendezvous: Xs[(i+1)&1] visible for next pass A
    }
}

extern "C" void kernel_launch(void* const* d_in, const int* in_sizes, int n_in,
                              void* d_out, int out_size, void* d_ws, size_t ws_size,
                              hipStream_t stream)
{
    const float* x   = (const float*)d_in[0];
    const float* hwt = (const float*)d_in[1];
    const float* wwt = (const float*)d_in[2];
    const float* hb  = (const float*)d_in[3];
    const float* wb  = (const float*)d_in[4];
    oversize_conv_v9<<<1024, 256, 0, stream>>>(x, hwt, wwt, hb, wb, (float*)d_out);
}